// Round 6
// baseline (107.292 us; speedup 1.0000x reference)
//
#include <hip/hip_runtime.h>
#include <hip/hip_fp16.h>

// NCC loss as two barrier-free streaming passes + tiny reduce.
// K1 (ncc_dw): thread-per-(h,w) column marches D with a 5ch x 9 register ring
//   (static slots via full unroll). After the D-window sums, the W 9-tap is
//   computed IN-WAVE via a shuffle tree (lanes = consecutive w; 64 lanes ->
//   56 outputs, 3 overlapping chunks per row). Writes DW-sums fp16-packed
//   (uint2 + uint = 12B/voxel). No LDS, no barriers.
// K2 (ncc_h): thread-per-(b,d,w) column marches H with a 5ch x 9 ring on the
//   packed DW-sums (coalesced: lanes = consecutive w), computes ncc in fp32,
//   accumulates, block-reduces to one partial. No global intermediate writes.
// K3: deterministic final reduction.

constexpr int BB = 2, DD = 160, HH = 160, WW = 160;
constexpr int SLICE = HH * WW;                        // 25600
constexpr long long NTOT = (long long)BB * DD * SLICE; // 8,192,000
constexpr int DSEG = 20, NDSEG = 8;                   // K1 d-segments
constexpr int HSEG = 20, NHSEG = 8;                   // K2 h-segments
constexpr int NPART = 200 * NHSEG;                    // 1600 partials

static __device__ __forceinline__ unsigned pkh(float a, float b) {
  __half2 h = __floats2half2_rn(a, b);               // RN: unbiased
  return __builtin_bit_cast(unsigned, h);
}
static __device__ __forceinline__ float2 uph(unsigned u) {
  return __half22float2(__builtin_bit_cast(__half2, u));
}

// 9-tap in-wave box sum: v[l] <- sum_{k=0..8} v[l+k]  (valid for l <= 55)
#define TAP9(v)                                                        \
  {                                                                    \
    float _t1 = __shfl_down(v, 1, 64), _t2 = __shfl_down(v, 2, 64);    \
    v = v + _t1 + _t2;                                                 \
    float _t3 = __shfl_down(v, 3, 64), _t6 = __shfl_down(v, 6, 64);    \
    v = v + _t3 + _t6;                                                 \
  }

// ---------------- K1: D-ring + in-wave W-sum ----------------
__global__ __launch_bounds__(256) void ncc_dw_kernel(
    const float* __restrict__ f, const float* __restrict__ w,
    uint2* __restrict__ o01, unsigned* __restrict__ o4) {
  const int tid = threadIdx.x;
  const int lane = tid & 63;
  const int wid = (blockIdx.x << 2) | (tid >> 6);  // 0..959 : (b, h, chunk)
  const int b = wid / 480;
  const int rem = wid % 480;
  const int h = rem / 3;
  const int ck = rem % 3;                          // w-chunk: outputs at 56*ck
  const int w_in = ck * 56 - 4 + lane;             // staggered input lane
  const int w_out = ck * 56 + lane;
  const bool vin = (unsigned)w_in < 160u;
  const bool vout = (lane < 56) && (w_out < 160);
  const int d0 = blockIdx.y * DSEG;
  const long long rowbase = (long long)b * DD * SLICE + (long long)h * WW;
  const float* fr = f + rowbase + w_in;
  const float* wr = w + rowbase + w_in;
  const long long obase = rowbase + w_out;

  float r0[9], r1[9], r2[9], r3[9], r4[9];
#pragma unroll
  for (int k = 0; k < 9; ++k) { r0[k] = r1[k] = r2[k] = r3[k] = r4[k] = 0.f; }
  float S0 = 0.f, S1 = 0.f, S2 = 0.f, S3 = 0.f, S4 = 0.f;

#pragma unroll
  for (int p = 0; p < DSEG + 8; ++p) {             // 28 steps
    const int j = d0 - 4 + p;                      // uniform guard
    float vf = 0.f, vw = 0.f;
    if ((unsigned)j < 160u) {
      if (vin) {
        vf = fr[(long long)j * SLICE];
        vw = wr[(long long)j * SLICE];
      }
    }
    const float a2 = vf * vf, a3 = vw * vw, a4 = vf * vw;
    const int sl = p % 9;                          // static after unroll
    S0 += vf - r0[sl]; r0[sl] = vf;
    S1 += vw - r1[sl]; r1[sl] = vw;
    S2 += a2 - r2[sl]; r2[sl] = a2;
    S3 += a3 - r3[sl]; r3[sl] = a3;
    S4 += a4 - r4[sl]; r4[sl] = a4;

    if (p >= 8) {
      float z0 = S0, z1 = S1, z2 = S2, z3 = S3, z4 = S4;
      TAP9(z0); TAP9(z1); TAP9(z2); TAP9(z3); TAP9(z4);
      if (vout) {
        const long long a = obase + (long long)(d0 + p - 8) * SLICE;
        o01[a] = make_uint2(pkh(z0, z1), pkh(z2, z3));
        o4[a] = pkh(z4, 0.f);
      }
    }
  }
}

// ---------------- K2: H-ring + ncc + reduce ----------------
__global__ __launch_bounds__(256) void ncc_h_kernel(
    const uint2* __restrict__ i01, const unsigned* __restrict__ i4,
    float* __restrict__ partials) {
  const int tid = threadIdx.x;
  const int g = blockIdx.x * 256 + tid;            // 0..51199 : (b, d, w)
  const int w = g % 160;
  const int t2 = g / 160;
  const int d = t2 % 160;
  const int b = t2 / 160;
  const int h0 = blockIdx.y * HSEG;
  const long long colbase = (long long)(b * DD + d) * SLICE + w;

  float r0[9], r1[9], r2[9], r3[9], r4[9];
#pragma unroll
  for (int k = 0; k < 9; ++k) { r0[k] = r1[k] = r2[k] = r3[k] = r4[k] = 0.f; }
  float S0 = 0.f, S1 = 0.f, S2 = 0.f, S3 = 0.f, S4 = 0.f, acc = 0.f;
  const float inv = 1.0f / 729.0f;

#pragma unroll
  for (int p = 0; p < HSEG + 8; ++p) {             // 28 steps
    const int j = h0 - 4 + p;                      // uniform guard
    float n0 = 0.f, n1 = 0.f, n2 = 0.f, n3 = 0.f, n4 = 0.f;
    if ((unsigned)j < 160u) {
      const long long a = colbase + (long long)j * WW;
      const uint2 u = i01[a];
      const float2 p01 = uph(u.x), p23 = uph(u.y);
      n0 = p01.x; n1 = p01.y; n2 = p23.x; n3 = p23.y;
      n4 = uph(i4[a]).x;
    }
    const int sl = p % 9;
    S0 += n0 - r0[sl]; r0[sl] = n0;
    S1 += n1 - r1[sl]; r1[sl] = n1;
    S2 += n2 - r2[sl]; r2[sl] = n2;
    S3 += n3 - r3[sl]; r3[sl] = n3;
    S4 += n4 - r4[sl]; r4[sl] = n4;

    if (p >= 8) {
      const float fm = S0 * inv, wm = S1 * inv;
      const float fv = S2 * inv - fm * fm;
      const float wv = S3 * inv - wm * wm;
      const float cov = S4 * inv - fm * wm;
      const float den = sqrtf(fmaxf(fv, 0.f) + 1e-8f) *
                        sqrtf(fmaxf(wv, 0.f) + 1e-8f);
      acc += fminf(1.f, fmaxf(-1.f, cov / den));
    }
  }

  __shared__ float red[256];
  red[tid] = acc;
  __syncthreads();
#pragma unroll
  for (int st = 128; st > 0; st >>= 1) {
    if (tid < st) red[tid] += red[tid + st];
    __syncthreads();
  }
  if (tid == 0) partials[blockIdx.y * gridDim.x + blockIdx.x] = red[0];
}

// ---------------- K3: final reduction ----------------
__global__ __launch_bounds__(1024) void ncc_final_kernel(
    const float* __restrict__ partials, float* __restrict__ out) {
  const int t = threadIdx.x;
  float a = 0.f;
  for (int i = t; i < NPART; i += 1024) a += partials[i];
#pragma unroll
  for (int off = 32; off > 0; off >>= 1) a += __shfl_down(a, off, 64);
  __shared__ float wr[16];
  if ((t & 63) == 0) wr[t >> 6] = a;
  __syncthreads();
  if (t == 0) {
    float s = 0.f;
#pragma unroll
    for (int k = 0; k < 16; ++k) s += wr[k];
    out[0] = -s * (1.0f / (float)NTOT);
  }
}

extern "C" void kernel_launch(void* const* d_in, const int* in_sizes, int n_in,
                              void* d_out, int out_size, void* d_ws, size_t ws_size,
                              hipStream_t stream) {
  const float* fixed = (const float*)d_in[0];
  const float* warped = (const float*)d_in[1];
  float* out = (float*)d_out;

  uint2* o01 = (uint2*)d_ws;                                     // 65.54 MB
  unsigned* o4 = (unsigned*)((char*)d_ws + (size_t)NTOT * 8);    // 32.77 MB
  float* partials = (float*)((char*)d_ws + (size_t)NTOT * 12);   // 6.4 KB

  dim3 g1(240, NDSEG);            // 960 waves x 8 d-segs = 1920 blocks
  ncc_dw_kernel<<<g1, dim3(256), 0, stream>>>(fixed, warped, o01, o4);

  dim3 g2(200, NHSEG);            // 1600 blocks
  ncc_h_kernel<<<g2, dim3(256), 0, stream>>>(o01, o4, partials);

  ncc_final_kernel<<<1, dim3(1024), 0, stream>>>(partials, out);
}

// Round 7
// 85.102 us; speedup vs baseline: 1.2607x; 1.2607x over previous
//
#include <hip/hip_runtime.h>
#include <hip/hip_fp16.h>

// NCC loss: three streaming passes, no 2D tiles, no main-loop barriers.
// K1 (ncc_h): thread per (b,d,w) marches H (8 segs x 20 + 8 halo) with a
//   5ch x 9 register ring (static slots via full unroll). Reads raw f,w
//   coalesced; writes 5 PLANAR fp16 streams (window H-sums of f,w,f2,w2,fw).
// K2 (ncc_dw): wave = (b,h,chunk); lanes = staggered w. Marches D (8 segs
//   x 20 + 8) reading the 5 planar fp16 streams (2B/lane, proven-fast
//   round-2 shape), 5ch x 9 ring for the D window, then the W 9-tap via a
//   4-shuffle tree per channel (proven round-6), then fp32 ncc + reduce.
// K3: deterministic final reduction.

constexpr int BB = 2, DD = 160, HH = 160, WW = 160;
constexpr int SLICE = HH * WW;                         // 25600
constexpr long long NTOT = (long long)BB * DD * SLICE; // 8,192,000
constexpr int HSEG = 20, NHSEG = 8;                    // K1 h-segments
constexpr int DSEG = 20, NDSEG = 8;                    // K2 d-segments
constexpr int NPART = 240 * NDSEG;                     // 1920 partials

// 9-tap in-wave box sum: v[l] <- sum_{k=0..8} v[l+k]  (valid for l <= 55)
#define TAP9(v)                                                        \
  {                                                                    \
    float _t1 = __shfl_down(v, 1, 64), _t2 = __shfl_down(v, 2, 64);    \
    v = v + _t1 + _t2;                                                 \
    float _t3 = __shfl_down(v, 3, 64), _t6 = __shfl_down(v, 6, 64);    \
    v = v + _t3 + _t6;                                                 \
  }

// ---------------- K1: H-axis window sums, planar fp16 out ----------------
__global__ __launch_bounds__(256) void ncc_h_kernel(
    const float* __restrict__ f, const float* __restrict__ w,
    __half* __restrict__ p0, __half* __restrict__ p1, __half* __restrict__ p2,
    __half* __restrict__ p3, __half* __restrict__ p4) {
  const int tid = threadIdx.x;
  const int g = blockIdx.x * 256 + tid;      // 0..51199 : (b,d,w)
  const int wq = g % 160;
  const int t2 = g / 160;
  const int d = t2 % 160;
  const int b = t2 / 160;
  const int h0 = blockIdx.y * HSEG;
  const long long base = (long long)(b * DD + d) * SLICE + wq;   // + j*WW

  float r0[9], r1[9], r2[9], r3[9], r4[9];
#pragma unroll
  for (int k = 0; k < 9; ++k) { r0[k] = r1[k] = r2[k] = r3[k] = r4[k] = 0.f; }
  float S0 = 0.f, S1 = 0.f, S2 = 0.f, S3 = 0.f, S4 = 0.f;

#pragma unroll
  for (int p = 0; p < HSEG + 8; ++p) {       // 28 steps
    const int j = h0 - 4 + p;                // block-uniform guard
    float vf = 0.f, vw = 0.f;
    if ((unsigned)j < 160u) {
      const long long a = base + (long long)j * WW;
      vf = f[a];
      vw = w[a];
    }
    const float a2 = vf * vf, a3 = vw * vw, a4 = vf * vw;
    const int sl = p % 9;                    // static after unroll
    S0 += vf - r0[sl]; r0[sl] = vf;
    S1 += vw - r1[sl]; r1[sl] = vw;
    S2 += a2 - r2[sl]; r2[sl] = a2;
    S3 += a3 - r3[sl]; r3[sl] = a3;
    S4 += a4 - r4[sl]; r4[sl] = a4;
    if (p >= 8) {
      const long long a = base + (long long)(h0 + p - 8) * WW;
      p0[a] = __float2half_rn(S0);
      p1[a] = __float2half_rn(S1);
      p2[a] = __float2half_rn(S2);
      p3[a] = __float2half_rn(S3);
      p4[a] = __float2half_rn(S4);
    }
  }
}

// ---------------- K2: D-ring + in-wave W-sum + ncc ----------------
__global__ __launch_bounds__(256) void ncc_dw_kernel(
    const __half* __restrict__ p0, const __half* __restrict__ p1,
    const __half* __restrict__ p2, const __half* __restrict__ p3,
    const __half* __restrict__ p4, float* __restrict__ partials) {
  const int tid = threadIdx.x;
  const int lane = tid & 63;
  const int wid = (blockIdx.x << 2) | (tid >> 6);  // 0..959 : (b,h,chunk)
  const int b = wid / 480;
  const int rem = wid % 480;
  const int h = rem / 3;
  const int ck = rem % 3;
  const int w_in = ck * 56 - 4 + lane;
  const int w_out = ck * 56 + lane;
  const bool vin = (unsigned)w_in < 160u;
  const bool vout = (lane < 56) && (w_out < 160);
  const int d0 = blockIdx.y * DSEG;
  const long long cb = (long long)b * DD * SLICE + (long long)h * WW + w_in;

  float r0[9], r1[9], r2[9], r3[9], r4[9];
#pragma unroll
  for (int k = 0; k < 9; ++k) { r0[k] = r1[k] = r2[k] = r3[k] = r4[k] = 0.f; }
  float S0 = 0.f, S1 = 0.f, S2 = 0.f, S3 = 0.f, S4 = 0.f, acc = 0.f;
  const float inv = 1.0f / 729.0f;

#pragma unroll
  for (int p = 0; p < DSEG + 8; ++p) {       // 28 steps
    const int j = d0 - 4 + p;                // uniform guard
    float n0 = 0.f, n1 = 0.f, n2 = 0.f, n3 = 0.f, n4 = 0.f;
    if ((unsigned)j < 160u) {
      if (vin) {
        const long long a = cb + (long long)j * SLICE;
        n0 = __half2float(p0[a]);
        n1 = __half2float(p1[a]);
        n2 = __half2float(p2[a]);
        n3 = __half2float(p3[a]);
        n4 = __half2float(p4[a]);
      }
    }
    const int sl = p % 9;                    // static after unroll
    S0 += n0 - r0[sl]; r0[sl] = n0;
    S1 += n1 - r1[sl]; r1[sl] = n1;
    S2 += n2 - r2[sl]; r2[sl] = n2;
    S3 += n3 - r3[sl]; r3[sl] = n3;
    S4 += n4 - r4[sl]; r4[sl] = n4;

    if (p >= 8) {
      float z0 = S0, z1 = S1, z2 = S2, z3 = S3, z4 = S4;
      TAP9(z0); TAP9(z1); TAP9(z2); TAP9(z3); TAP9(z4);
      if (vout) {
        const float fm = z0 * inv, wm = z1 * inv;
        const float fv = z2 * inv - fm * fm;
        const float wv = z3 * inv - wm * wm;
        const float cov = z4 * inv - fm * wm;
        const float den = sqrtf(fmaxf(fv, 0.f) + 1e-8f) *
                          sqrtf(fmaxf(wv, 0.f) + 1e-8f);
        acc += fminf(1.f, fmaxf(-1.f, cov / den));
      }
    }
  }

  __shared__ float red[256];
  red[tid] = acc;
  __syncthreads();
#pragma unroll
  for (int st = 128; st > 0; st >>= 1) {
    if (tid < st) red[tid] += red[tid + st];
    __syncthreads();
  }
  if (tid == 0) partials[blockIdx.y * gridDim.x + blockIdx.x] = red[0];
}

// ---------------- K3: final reduction ----------------
__global__ __launch_bounds__(1024) void ncc_final_kernel(
    const float* __restrict__ partials, float* __restrict__ out) {
  const int t = threadIdx.x;
  float a = 0.f;
  for (int i = t; i < NPART; i += 1024) a += partials[i];
#pragma unroll
  for (int off = 32; off > 0; off >>= 1) a += __shfl_down(a, off, 64);
  __shared__ float wr[16];
  if ((t & 63) == 0) wr[t >> 6] = a;
  __syncthreads();
  if (t == 0) {
    float s = 0.f;
#pragma unroll
    for (int k = 0; k < 16; ++k) s += wr[k];
    out[0] = -s * (1.0f / (float)NTOT);
  }
}

extern "C" void kernel_launch(void* const* d_in, const int* in_sizes, int n_in,
                              void* d_out, int out_size, void* d_ws, size_t ws_size,
                              hipStream_t stream) {
  const float* fixed = (const float*)d_in[0];
  const float* warped = (const float*)d_in[1];
  float* out = (float*)d_out;

  __half* p0 = (__half*)d_ws;                        // 5 planes x 16.4 MB
  __half* p1 = p0 + NTOT;
  __half* p2 = p1 + NTOT;
  __half* p3 = p2 + NTOT;
  __half* p4 = p3 + NTOT;
  float* partials = (float*)((char*)d_ws + (size_t)NTOT * 10);  // 7.7 KB

  dim3 g1(200, NHSEG);            // 1600 blocks x 256
  ncc_h_kernel<<<g1, dim3(256), 0, stream>>>(fixed, warped, p0, p1, p2, p3, p4);

  dim3 g2(240, NDSEG);            // 1920 blocks x 256 (960 waves x 8 segs)
  ncc_dw_kernel<<<g2, dim3(256), 0, stream>>>(p0, p1, p2, p3, p4, partials);

  ncc_final_kernel<<<1, dim3(1024), 0, stream>>>(partials, out);
}